// Round 1
// baseline (122.219 us; speedup 1.0000x reference)
//
#include <hip/hip_runtime.h>

typedef _Float16 f16;
typedef _Float16 f16x8 __attribute__((ext_vector_type(8)));
typedef _Float16 f16x4 __attribute__((ext_vector_type(4)));
typedef float    f32x4 __attribute__((ext_vector_type(4)));

__device__ __forceinline__ float sigmf(float x) {
    return __builtin_amdgcn_rcpf(1.0f + __expf(-x));
}
__device__ __forceinline__ float tanhf_fast(float x) {
    // tanh(x) = 2*sigmoid(2x) - 1 ; saturates correctly for large |x|
    return 2.0f * sigmf(2.0f * x) - 1.0f;
}

// LDS geometry
constexpr int WG_SZ = 12 * 2048;   // gates W^T: [12 kb][256 n][8] f16  (K=96: h(64)|x(5)|zeros)
constexpr int W1_SZ = 8 * 2048;    // W1^T: [8][256][8]
constexpr int W2_SZ = 32 * 512;    // W2^T: [32][64][8]
constexpr int W3_SZ = 8 * 256;     // W3^T: [8][32][8]
constexpr int W4_SZ = 4 * 128;     // W4^T: [4][16][8]
constexpr int KBS   = 1040;        // ABUF kb-slab stride in f16 elems (128 rows * 8 + 16 pad -> +8 banks/kb)
constexpr int AB_SZ = 12 * KBS;

__global__ __launch_bounds__(512, 1)
void lstmdqn_fused(const float* __restrict__ xg,  const float* __restrict__ h0g,
                   const float* __restrict__ c0g,
                   const float* __restrict__ Wih, const float* __restrict__ Whh,
                   const float* __restrict__ bih, const float* __restrict__ bhh,
                   const float* __restrict__ w1p, const float* __restrict__ b1p,
                   const float* __restrict__ w2p, const float* __restrict__ b2p,
                   const float* __restrict__ w3p, const float* __restrict__ b3p,
                   const float* __restrict__ w4p, const float* __restrict__ b4p,
                   const float* __restrict__ whp, const float* __restrict__ bhp,
                   float* __restrict__ out, int Bsz, int ntiles) {
    __shared__ f16 sWG[WG_SZ];
    __shared__ f16 sW1[W1_SZ];
    __shared__ f16 sW2[W2_SZ];
    __shared__ f16 sW3[W3_SZ];
    __shared__ f16 sW4[W4_SZ];
    __shared__ f16 sAB[AB_SZ];
    __shared__ float sBG[256], sB1[256], sB2[64], sB3[32], sB4[16];
    __shared__ float sWH[48], sBH[3];
    __shared__ float sZ4[8 * 16 * 17];

    const int tid  = threadIdx.x;
    const int w    = tid >> 6;
    const int l    = tid & 63;
    const int lrow = l & 15;       // A row / B col / D col within tile
    const int lk   = l >> 4;       // k-chunk selector (0..3)
    const int wrow = w * 16;       // this wave's row base in LDS buffers

    // ---------------- weight staging (once per block) ----------------
    for (int idx = tid; idx < WG_SZ; idx += 512) {
        int kb = idx >> 11, n = (idx >> 3) & 255, j = idx & 7;
        int k = kb * 8 + j;
        float v = 0.0f;
        if (k < 64)      v = Whh[n * 64 + k];
        else if (k < 69) v = Wih[n * 5 + (k - 64)];
        sWG[idx] = (f16)v;
    }
    for (int idx = tid; idx < W1_SZ; idx += 512) {
        int kb = idx >> 11, n = (idx >> 3) & 255, j = idx & 7;
        sW1[idx] = (f16)w1p[n * 64 + kb * 8 + j];
    }
    for (int idx = tid; idx < W2_SZ; idx += 512) {
        int kb = idx >> 9, n = (idx >> 3) & 63, j = idx & 7;
        sW2[idx] = (f16)w2p[n * 256 + kb * 8 + j];
    }
    for (int idx = tid; idx < W3_SZ; idx += 512) {
        int kb = idx >> 8, n = (idx >> 3) & 31, j = idx & 7;
        sW3[idx] = (f16)w3p[n * 64 + kb * 8 + j];
    }
    for (int idx = tid; idx < W4_SZ; idx += 512) {
        int kb = idx >> 7, n = (idx >> 3) & 15, j = idx & 7;
        sW4[idx] = (f16)w4p[n * 32 + kb * 8 + j];
    }
    // zero the x-pad region of ABUF (kb 8..11, all 128 rows) once; x overwrites j<5 of kb8 per step
    for (int idx = tid; idx < 4 * 128 * 8; idx += 512) {
        int kb = 8 + (idx >> 10), r = (idx >> 3) & 127, j = idx & 7;
        sAB[kb * KBS + r * 8 + j] = (f16)0.0f;
    }
    if (tid < 256) { sBG[tid] = bih[tid] + bhh[tid]; sB1[tid] = b1p[tid]; }
    if (tid < 64)  sB2[tid] = b2p[tid];
    if (tid < 32)  sB3[tid] = b3p[tid];
    if (tid < 16)  sB4[tid] = b4p[tid];
    if (tid < 48)  sWH[tid] = whp[tid];
    if (tid < 3)   sBH[tid] = bhp[tid];
    __syncthreads();
    // ---- from here on: every wave touches only its own 16 LDS rows -> no barriers needed ----

    for (int tile = blockIdx.x * 8 + w; tile < ntiles; tile += gridDim.x * 8) {
        const int rbase = tile * 16;

        // stage h0 -> ABUF kb0..7 (f16), vectorized: wave covers its 16x64 block
        {
            const float* hp = h0g + (size_t)rbase * 64;
            #pragma unroll
            for (int e = 0; e < 4; ++e) {
                float4 v = *(const float4*)(hp + e * 256 + l * 4);
                int r  = wrow + 4 * e + (l >> 4);
                int kb = (l >> 1) & 7;
                int j  = 4 * (l & 1);
                f16x4 h4 = { (f16)v.x, (f16)v.y, (f16)v.z, (f16)v.w };
                *reinterpret_cast<f16x4*>(&sAB[kb * KBS + r * 8 + j]) = h4;
            }
        }
        // c0 -> registers in D-fragment layout: creg[ct][q] = c[4*lk+q][ct*16+lrow]
        float creg[4][4];
        #pragma unroll
        for (int ct = 0; ct < 4; ++ct)
            #pragma unroll
            for (int q = 0; q < 4; ++q)
                creg[ct][q] = c0g[(size_t)(rbase + 4 * lk + q) * 64 + ct * 16 + lrow];

        // ---------------- 2 LSTM steps ----------------
        #pragma unroll
        for (int t = 0; t < 2; ++t) {
            // stage x_t (5 features) into ABUF kb8 j<5, own rows
            {
                const float* xp = xg + (size_t)t * Bsz * 5 + (size_t)rbase * 5;
                int r = l / 5, j = l - 5 * r;            // idx = l (0..63)
                if (l < 64) sAB[8 * KBS + (wrow + r) * 8 + j] = (f16)xp[l];
                if (l < 16) {
                    int idx = 64 + l; int r2 = idx / 5, j2 = idx - 5 * r2;
                    sAB[8 * KBS + (wrow + r2) * 8 + j2] = (f16)xp[idx];
                }
            }
            // A fragments (K=96 -> 3 k-tiles)
            f16x8 af0 = *reinterpret_cast<const f16x8*>(&sAB[(0 + lk) * KBS + (wrow + lrow) * 8]);
            f16x8 af1 = *reinterpret_cast<const f16x8*>(&sAB[(4 + lk) * KBS + (wrow + lrow) * 8]);
            f16x8 af2 = *reinterpret_cast<const f16x8*>(&sAB[(8 + lk) * KBS + (wrow + lrow) * 8]);

            f32x4 acc[16];
            #pragma unroll
            for (int ct = 0; ct < 16; ++ct) {
                float bv = sBG[ct * 16 + lrow];
                f32x4 a = { bv, bv, bv, bv };
                a = __builtin_amdgcn_mfma_f32_16x16x32_f16(af0,
                        *reinterpret_cast<const f16x8*>(&sWG[(0 + lk) * 2048 + (ct * 16 + lrow) * 8]), a, 0, 0, 0);
                a = __builtin_amdgcn_mfma_f32_16x16x32_f16(af1,
                        *reinterpret_cast<const f16x8*>(&sWG[(4 + lk) * 2048 + (ct * 16 + lrow) * 8]), a, 0, 0, 0);
                a = __builtin_amdgcn_mfma_f32_16x16x32_f16(af2,
                        *reinterpret_cast<const f16x8*>(&sWG[(8 + lk) * 2048 + (ct * 16 + lrow) * 8]), a, 0, 0, 0);
                acc[ct] = a;
            }
            // elementwise LSTM cell (gate order i,f,g,o along cols): fully in-register
            #pragma unroll
            for (int ct = 0; ct < 4; ++ct) {
                #pragma unroll
                for (int q = 0; q < 4; ++q) {
                    float iv = sigmf(acc[ct][q]);
                    float fv = sigmf(acc[4 + ct][q]);
                    float gv = tanhf_fast(acc[8 + ct][q]);
                    float ov = sigmf(acc[12 + ct][q]);
                    float c  = fv * creg[ct][q] + iv * gv;
                    creg[ct][q] = c;
                    float h = ov * tanhf_fast(c);
                    if (t == 1) h = fmaxf(h, 0.0f);      // z0 = relu(h2)
                    int n = ct * 16 + lrow;
                    sAB[(n >> 3) * KBS + (wrow + 4 * lk + q) * 8 + (n & 7)] = (f16)h;
                }
            }
        }

        // ---------------- z1 = relu(z0 @ W1^T + b1), [16,256], K=64 ----------------
        {
            f16x8 a0 = *reinterpret_cast<const f16x8*>(&sAB[(0 + lk) * KBS + (wrow + lrow) * 8]);
            f16x8 a1 = *reinterpret_cast<const f16x8*>(&sAB[(4 + lk) * KBS + (wrow + lrow) * 8]);
            f32x4 acc1[16];
            #pragma unroll
            for (int ct = 0; ct < 16; ++ct) {
                float bv = sB1[ct * 16 + lrow];
                f32x4 a = { bv, bv, bv, bv };
                a = __builtin_amdgcn_mfma_f32_16x16x32_f16(a0,
                        *reinterpret_cast<const f16x8*>(&sW1[(0 + lk) * 2048 + (ct * 16 + lrow) * 8]), a, 0, 0, 0);
                a = __builtin_amdgcn_mfma_f32_16x16x32_f16(a1,
                        *reinterpret_cast<const f16x8*>(&sW1[(4 + lk) * 2048 + (ct * 16 + lrow) * 8]), a, 0, 0, 0);
                acc1[ct] = a;
            }
            // ------------ z2 = relu(z1 @ W2^T + b2), [16,64], K=256 in 4 chunks ------------
            f32x4 acc2[4];
            #pragma unroll
            for (int ct2 = 0; ct2 < 4; ++ct2) {
                float bv = sB2[ct2 * 16 + lrow];
                acc2[ct2] = (f32x4){ bv, bv, bv, bv };
            }
            #pragma unroll
            for (int cc = 0; cc < 4; ++cc) {
                #pragma unroll
                for (int ctl = 0; ctl < 4; ++ctl)
                    #pragma unroll
                    for (int q = 0; q < 4; ++q) {
                        float v = fmaxf(acc1[cc * 4 + ctl][q], 0.0f);
                        int n = ctl * 16 + lrow;
                        sAB[(n >> 3) * KBS + (wrow + 4 * lk + q) * 8 + (n & 7)] = (f16)v;
                    }
                f16x8 b0 = *reinterpret_cast<const f16x8*>(&sAB[(0 + lk) * KBS + (wrow + lrow) * 8]);
                f16x8 b1 = *reinterpret_cast<const f16x8*>(&sAB[(4 + lk) * KBS + (wrow + lrow) * 8]);
                #pragma unroll
                for (int ct2 = 0; ct2 < 4; ++ct2) {
                    acc2[ct2] = __builtin_amdgcn_mfma_f32_16x16x32_f16(b0,
                        *reinterpret_cast<const f16x8*>(&sW2[(cc * 8 + 0 + lk) * 512 + (ct2 * 16 + lrow) * 8]), acc2[ct2], 0, 0, 0);
                    acc2[ct2] = __builtin_amdgcn_mfma_f32_16x16x32_f16(b1,
                        *reinterpret_cast<const f16x8*>(&sW2[(cc * 8 + 4 + lk) * 512 + (ct2 * 16 + lrow) * 8]), acc2[ct2], 0, 0, 0);
                }
            }
            // ------------ z3 = relu(z2 @ W3^T + b3), [16,32], K=64 ------------
            #pragma unroll
            for (int ct2 = 0; ct2 < 4; ++ct2)
                #pragma unroll
                for (int q = 0; q < 4; ++q) {
                    float v = fmaxf(acc2[ct2][q], 0.0f);
                    int n = ct2 * 16 + lrow;
                    sAB[(n >> 3) * KBS + (wrow + 4 * lk + q) * 8 + (n & 7)] = (f16)v;
                }
            f16x8 a30 = *reinterpret_cast<const f16x8*>(&sAB[(0 + lk) * KBS + (wrow + lrow) * 8]);
            f16x8 a31 = *reinterpret_cast<const f16x8*>(&sAB[(4 + lk) * KBS + (wrow + lrow) * 8]);
            f32x4 acc3[2];
            #pragma unroll
            for (int ct3 = 0; ct3 < 2; ++ct3) {
                float bv = sB3[ct3 * 16 + lrow];
                f32x4 a = { bv, bv, bv, bv };
                a = __builtin_amdgcn_mfma_f32_16x16x32_f16(a30,
                        *reinterpret_cast<const f16x8*>(&sW3[(0 + lk) * 256 + (ct3 * 16 + lrow) * 8]), a, 0, 0, 0);
                a = __builtin_amdgcn_mfma_f32_16x16x32_f16(a31,
                        *reinterpret_cast<const f16x8*>(&sW3[(4 + lk) * 256 + (ct3 * 16 + lrow) * 8]), a, 0, 0, 0);
                acc3[ct3] = a;
            }
            // ------------ z4 = relu(z3 @ W4^T + b4), [16,16], K=32 ------------
            #pragma unroll
            for (int ct3 = 0; ct3 < 2; ++ct3)
                #pragma unroll
                for (int q = 0; q < 4; ++q) {
                    float v = fmaxf(acc3[ct3][q], 0.0f);
                    int n = ct3 * 16 + lrow;               // 0..31 -> kb 0..3
                    sAB[(n >> 3) * KBS + (wrow + 4 * lk + q) * 8 + (n & 7)] = (f16)v;
                }
            f16x8 a4 = *reinterpret_cast<const f16x8*>(&sAB[lk * KBS + (wrow + lrow) * 8]);
            float bv4 = sB4[lrow];
            f32x4 acc4 = { bv4, bv4, bv4, bv4 };
            acc4 = __builtin_amdgcn_mfma_f32_16x16x32_f16(a4,
                        *reinterpret_cast<const f16x8*>(&sW4[lk * 128 + lrow * 8]), acc4, 0, 0, 0);
            // ------------ head: out = relu(z4) @ Wh^T + bh, [16,3] on VALU ------------
            #pragma unroll
            for (int q = 0; q < 4; ++q)
                sZ4[w * 272 + (4 * lk + q) * 17 + lrow] = fmaxf(acc4[q], 0.0f);
            if (l < 48) {
                int r = l / 3, a = l - 3 * r;
                float s = sBH[a];
                #pragma unroll
                for (int c = 0; c < 16; ++c)
                    s += sZ4[w * 272 + r * 17 + c] * sWH[a * 16 + c];
                out[(size_t)rbase * 3 + l] = s;
            }
        }
    }
}

extern "C" void kernel_launch(void* const* d_in, const int* in_sizes, int n_in,
                              void* d_out, int out_size, void* d_ws, size_t ws_size,
                              hipStream_t stream) {
    const float* x   = (const float*)d_in[0];
    const float* h0  = (const float*)d_in[1];
    const float* c0  = (const float*)d_in[2];
    const float* Wih = (const float*)d_in[3];
    const float* Whh = (const float*)d_in[4];
    const float* bih = (const float*)d_in[5];
    const float* bhh = (const float*)d_in[6];
    const float* w1  = (const float*)d_in[7];
    const float* b1  = (const float*)d_in[8];
    const float* w2  = (const float*)d_in[9];
    const float* b2  = (const float*)d_in[10];
    const float* w3  = (const float*)d_in[11];
    const float* b3  = (const float*)d_in[12];
    const float* w4  = (const float*)d_in[13];
    const float* b4  = (const float*)d_in[14];
    const float* wh  = (const float*)d_in[15];
    const float* bh  = (const float*)d_in[16];

    int Bsz    = in_sizes[1] / 64;   // h0 is [B, 64]
    int ntiles = Bsz / 16;
    int grid   = 512;                // 8 wave-tiles per block; 4 persistent iterations each

    lstmdqn_fused<<<grid, 512, 0, stream>>>(x, h0, c0, Wih, Whh, bih, bhh,
                                            w1, b1, w2, b2, w3, b3, w4, b4, wh, bh,
                                            (float*)d_out, Bsz, ntiles);
}